// Round 10
// baseline (2785.321 us; speedup 1.0000x reference)
//
#include <hip/hip_runtime.h>

// N=64, T=512, D=H=512.
//   xw = x @ Wx + b   -> d_out (fp32), big MFMA GEMM
//   h_t = tanh(h_{t-1} @ Wh + xw_t) -> overwrites d_out in place
//
// rnn_scan v9: 8 blocks = 4 batch-groups x 2 column-halves. Cross-block
// h-exchange through L3 via device-scope (AGENT) relaxed atomics -- NO
// threadfence/wbl2 (round-2's 16us/step mistake), NO acquire/buffer_inv.
// Protocol per step t: [phase1 MFMA own k-slice from LDS] -> poll peer seq
// flag >= t (flag observed => peer h_{t-1} at L3 => later loads see it) ->
// 16x relaxed-agent u64 loads of peer frags -> [phase2 MFMA] -> epilogue:
// tanh, fp32 out store, bf16 ds_write own LDS + relaxed-agent u64 stores to
// own hx buffer -> __syncthreads (drains vmcnt: hx stores at L3) -> lane 0
// releases self seq = t+1 (relaxed agent).
// Per-wave: 16kk x 2cc weights = 128 regs (all Wh register-resident),
// acc 8, xwv 8 -> ~200 regs at 2 waves/SIMD (256 budget, round-9 lesson:
// unified file, v8's 256-frag attempt spilled). LDS = 16 KB h ping-pong only.
// Per-SIMD MFMA = 64/step = 1242 cy (half of v7).

typedef __attribute__((ext_vector_type(8))) short short8;
typedef __attribute__((ext_vector_type(4))) float f32x4;

#define DIM 512
#define T_S 512

union Frag { uint4 v; short8 s; unsigned short u[8]; unsigned long long ll[2]; };

static __device__ __forceinline__ unsigned short f2bf(float f) {
  union { float f; unsigned u; } v;
  v.f = f;
  unsigned r = v.u + 0x7FFFu + ((v.u >> 16) & 1u);
  return (unsigned short)(r >> 16);
}

static __device__ __forceinline__ unsigned cvt_pk_bf16(float a, float b) {
  unsigned r;
  asm("v_cvt_pk_bf16_f32 %0, %1, %2" : "=v"(r) : "v"(a), "v"(b));
  return r;  // lo16 = bf16(a), hi16 = bf16(b), RNE
}

static __device__ __forceinline__ float fast_tanh(float s) {
  float e = __builtin_amdgcn_exp2f(2.885390082f * s);
  return 1.0f - 2.0f * __builtin_amdgcn_rcpf(e + 1.0f);
}

// ---------------------------------------------------------------------------
// Pack W (512x512 fp32) into bf16 MFMA fragments (A/B-symmetric layout).
// Frag (kk, cc): lane l holds W[k=32kk+8(l>>4)+j][col=16cc+(l&15)], j=0..7,
// at dst[(kk*32+cc)*64 + lane].
// ---------------------------------------------------------------------------
__global__ __launch_bounds__(64) void prepack(const float* __restrict__ Wx,
                                              const float* __restrict__ Wh,
                                              uint4* __restrict__ wxb,
                                              uint4* __restrict__ whb) {
  int bid = blockIdx.x;
  int mat = bid >> 9;
  int idx = bid & 511;
  int kk = idx >> 5, cc = idx & 31;
  int lane = threadIdx.x;
  int lo = lane & 15, hi = lane >> 4;
  const float* src = mat ? Wh : Wx;
  uint4* dst = mat ? whb : wxb;
  int col = cc * 16 + lo;
  int kbase = kk * 32 + hi * 8;
  Frag fr;
#pragma unroll
  for (int j = 0; j < 8; ++j)
    fr.u[j] = f2bf(src[(size_t)(kbase + j) * DIM + col]);
  dst[(kk * 32 + cc) * 64 + lane] = fr.v;
}

// ---------------------------------------------------------------------------
// xw = x @ Wx + b -> out (fp32). M=32768, K=N=512. Unchanged.
// ---------------------------------------------------------------------------
__global__ __launch_bounds__(256) void gemm_xw(const float* __restrict__ x,
                                               const uint4* __restrict__ wxb,
                                               const float* __restrict__ bias,
                                               float* __restrict__ out) {
  int bid = blockIdx.x;
  int m = bid >> 2, nb = bid & 3;
  int wave = threadIdx.x >> 6, lane = threadIdx.x & 63;
  int lo = lane & 15, hi = lane >> 4;
  int rowbase = m * 64;
  int colbase = nb * 128 + wave * 32;

  f32x4 acc[4][2];
#pragma unroll
  for (int mi = 0; mi < 4; ++mi)
#pragma unroll
    for (int ni = 0; ni < 2; ++ni) acc[mi][ni] = (f32x4){0.f, 0.f, 0.f, 0.f};

  for (int kk = 0; kk < 16; ++kk) {
    short8 afrag[4];
#pragma unroll
    for (int mi = 0; mi < 4; ++mi) {
      const float* ap = x + (size_t)(rowbase + mi * 16 + lo) * DIM + kk * 32 + hi * 8;
      float4 f0 = *(const float4*)ap;
      float4 f1 = *(const float4*)(ap + 4);
      Frag a;
      a.u[0] = f2bf(f0.x); a.u[1] = f2bf(f0.y); a.u[2] = f2bf(f0.z); a.u[3] = f2bf(f0.w);
      a.u[4] = f2bf(f1.x); a.u[5] = f2bf(f1.y); a.u[6] = f2bf(f1.z); a.u[7] = f2bf(f1.w);
      afrag[mi] = a.s;
    }
#pragma unroll
    for (int ni = 0; ni < 2; ++ni) {
      int cc = nb * 8 + wave * 2 + ni;
      Frag b;
      b.v = wxb[(kk * 32 + cc) * 64 + lane];
#pragma unroll
      for (int mi = 0; mi < 4; ++mi)
        acc[mi][ni] = __builtin_amdgcn_mfma_f32_16x16x32_bf16(afrag[mi], b.s, acc[mi][ni], 0, 0, 0);
    }
  }
#pragma unroll
  for (int ni = 0; ni < 2; ++ni) {
    int col = colbase + ni * 16 + lo;
    float bv = bias[col];
#pragma unroll
    for (int mi = 0; mi < 4; ++mi)
#pragma unroll
      for (int r = 0; r < 4; ++r) {
        int row = rowbase + mi * 16 + hi * 4 + r;
        out[(size_t)row * DIM + col] = acc[mi][ni][r] + bv;
      }
  }
}

// ---------------------------------------------------------------------------
// Recurrent scan v9. grid = 8 blocks x 512 thr (8 waves, 2/SIMD).
// Block (g = bid>>1, half = bid&1): batch rows [16g,16g+16),
// cols [256*half, 256*half+256). Wave w: 32 cols (cc = 16*half + 2w + {0,1}).
// Own-half h in LDS [buf][n][k_local] bf16, XOR-swizzled
// (byte = n*512 + ((k*2)^((n&7)<<4))); peer half exchanged via hx in L3.
// ---------------------------------------------------------------------------
__shared__ unsigned short hbuf2[2][16 * 256];  // 16 KB ping/pong

template <int BUF, bool FIRST>
static __device__ __forceinline__ void step_body(
    int t, int half, int w, int tid, int lo, int hi,
    const uint4 (&bw)[16][2],
    const uint4* const (&rdp)[8], uint2* const (&wrp)[2],
    float (&xwv)[8], float*& gp,
    const char* hx_peer, char* hx_self, const float* h0row,
    const unsigned* peer_seq, unsigned* self_seq) {
  // acc starts at xw (lane: n=lo, local cols w*32 + 16i + 4hi + r)
  f32x4 acc[2];
#pragma unroll
  for (int i = 0; i < 2; ++i)
    acc[i] = (f32x4){xwv[i * 4 + 0], xwv[i * 4 + 1], xwv[i * 4 + 2], xwv[i * 4 + 3]};

  // prefetch xw(t+1): 2x dwordx4
  const float* lp = gp + ((t < T_S - 1) ? DIM : 0);
#pragma unroll
  for (int i = 0; i < 2; ++i) {
    float4 f = *(const float4*)(lp + i * 16);
    xwv[i * 4 + 0] = f.x; xwv[i * 4 + 1] = f.y;
    xwv[i * 4 + 2] = f.z; xwv[i * 4 + 3] = f.w;
  }

  // phase 1: own k-slice (local kk 0..7 -> bw[0..7]) from LDS
#pragma unroll
  for (int kkl = 0; kkl < 8; ++kkl) {
    Frag hf; hf.v = rdp[kkl][BUF * 512];  // +8192B for buffer 1
#pragma unroll
    for (int i = 0; i < 2; ++i) {
      Frag a; a.v = bw[kkl][i];
      acc[i] = __builtin_amdgcn_mfma_f32_16x16x32_bf16(a.s, hf.s, acc[i], 0, 0, 0);
    }
  }

  // peer h_{t-1} fragments
  Frag pf[8];
  if (FIRST) {
    // step 0: peer half of h0 directly from input (fp32 -> bf16, same rounding)
    const float* pb = h0row + (half ^ 1) * 256;
#pragma unroll
    for (int kkl = 0; kkl < 8; ++kkl) {
      const float* p = pb + kkl * 32 + hi * 8;
      float4 f0 = *(const float4*)p;
      float4 f1 = *(const float4*)(p + 4);
      pf[kkl].u[0] = f2bf(f0.x); pf[kkl].u[1] = f2bf(f0.y);
      pf[kkl].u[2] = f2bf(f0.z); pf[kkl].u[3] = f2bf(f0.w);
      pf[kkl].u[4] = f2bf(f1.x); pf[kkl].u[5] = f2bf(f1.y);
      pf[kkl].u[6] = f2bf(f1.z); pf[kkl].u[7] = f2bf(f1.w);
    }
  } else {
    // poll peer flag (monotone); flag >= t => peer h_{t-1} visible at L3
    while (__hip_atomic_load(peer_seq, __ATOMIC_RELAXED,
                             __HIP_MEMORY_SCOPE_AGENT) < (unsigned)t)
      __builtin_amdgcn_s_sleep(1);
    __builtin_amdgcn_sched_barrier(0);
    const char* hp = hx_peer + (BUF ^ 1) * 8192 + lo * 512;
#pragma unroll
    for (int kkl = 0; kkl < 8; ++kkl) {
      pf[kkl].ll[0] = __hip_atomic_load(
          (const unsigned long long*)(hp + kkl * 64 + hi * 16),
          __ATOMIC_RELAXED, __HIP_MEMORY_SCOPE_AGENT);
      pf[kkl].ll[1] = __hip_atomic_load(
          (const unsigned long long*)(hp + kkl * 64 + hi * 16 + 8),
          __ATOMIC_RELAXED, __HIP_MEMORY_SCOPE_AGENT);
    }
  }

  // phase 2: peer k-slice (bw[8..15])
#pragma unroll
  for (int kkl = 0; kkl < 8; ++kkl) {
#pragma unroll
    for (int i = 0; i < 2; ++i) {
      Frag a; a.v = bw[8 + kkl][i];
      acc[i] = __builtin_amdgcn_mfma_f32_16x16x32_bf16(a.s, pf[kkl].s, acc[i], 0, 0, 0);
    }
  }

  // epilogue: lane owns n=lo, 4 consecutive local cols per acc group
  char* hs = hx_self + BUF * 8192 + lo * 512 + w * 64 + 8 * hi;
#pragma unroll
  for (int i = 0; i < 2; ++i) {
    float t0 = fast_tanh(acc[i][0]);
    float t1 = fast_tanh(acc[i][1]);
    float t2 = fast_tanh(acc[i][2]);
    float t3 = fast_tanh(acc[i][3]);
    *(float4*)(gp + i * 16) = (float4){t0, t1, t2, t3};  // fp32 out
    uint2 u;
    u.x = cvt_pk_bf16(t0, t1);
    u.y = cvt_pk_bf16(t2, t3);
    wrp[i][(BUF ^ 1) * 1024] = u;                        // ds_write_b64 (LDS)
    unsigned long long uv = ((unsigned long long)u.y << 32) | u.x;
    __hip_atomic_store((unsigned long long*)(hs + i * 32), uv,
                       __ATOMIC_RELAXED, __HIP_MEMORY_SCOPE_AGENT);
  }
  gp += DIM;

  // barrier drains vmcnt (hx stores at coherence point) + lgkm (LDS writes)
  __syncthreads();
  if (tid == 0)
    __hip_atomic_store(self_seq, (unsigned)(t + 1), __ATOMIC_RELAXED,
                       __HIP_MEMORY_SCOPE_AGENT);
}

__global__ __launch_bounds__(512, 2) void rnn_scan(const float* __restrict__ h0,
                                                   const uint4* __restrict__ whb,
                                                   float* __restrict__ out,
                                                   char* __restrict__ hx,
                                                   unsigned* __restrict__ seq) {
  int bid = blockIdx.x;
  int g = bid >> 1, half = bid & 1;
  int tid = threadIdx.x;
  int w = tid >> 6, lane = tid & 63;
  int lo = lane & 15, hi = lane >> 4;
  int msk = (lo & 7) << 4;

  // weights, locally ordered: j 0..7 = own k-slice, j 8..15 = peer k-slice
  // (kept compile-time-indexed in the loop; rule-#20 safe)
  uint4 bw[16][2];
#pragma unroll
  for (int j = 0; j < 16; ++j) {
    int kk = (j < 8) ? (half * 8 + j) : ((half ^ 1) * 8 + (j - 8));
#pragma unroll
    for (int i = 0; i < 2; ++i) {
      int cc = half * 16 + w * 2 + i;
      bw[j][i] = whb[(kk * 32 + cc) * 64 + lane];
    }
  }

  // loop-invariant LDS addresses (buffer 0; buffer 1 via +8192B imm)
  const uint4* rdp[8];
#pragma unroll
  for (int kkl = 0; kkl < 8; ++kkl)
    rdp[kkl] = (const uint4*)((const char*)hbuf2 + lo * 512 +
                              ((kkl * 64 + hi * 16) ^ msk));
  uint2* wrp[2];
#pragma unroll
  for (int i = 0; i < 2; ++i)
    wrp[i] = (uint2*)((char*)hbuf2 + lo * 512 +
                      ((w * 64 + i * 32 + 8 * hi) ^ msk));

  char* hx_self = hx + (g * 2 + half) * 16384;
  const char* hx_peer = hx + (g * 2 + (half ^ 1)) * 16384;
  unsigned* self_seq = seq + (g * 2 + half) * 16;        // 64B apart
  const unsigned* peer_seq = seq + (g * 2 + (half ^ 1)) * 16;

  const float* h0row = h0 + (size_t)(g * 16 + lo) * DIM;

  // own-half h_0 -> LDS buffer 0 (bf16, swizzled)
#pragma unroll
  for (int i = 0; i < 2; ++i) {
    const float* hp = h0row + half * 256 + w * 32 + i * 16 + hi * 4;
    float4 f = *(const float4*)hp;
    uint2 u;
    u.x = (unsigned)f2bf(f.x) | ((unsigned)f2bf(f.y) << 16);
    u.y = (unsigned)f2bf(f.z) | ((unsigned)f2bf(f.w) << 16);
    wrp[i][0] = u;
  }

  // running global pointer: lane -> out[n=16g+lo][t=0][256*half + 32w + 4hi]
  float* gp = out + ((size_t)(g * 16 + lo) * T_S) * DIM + half * 256 + w * 32 + hi * 4;

  // prime xw for t=0
  float xwv[8];
#pragma unroll
  for (int i = 0; i < 2; ++i) {
    float4 f = *(const float4*)(gp + i * 16);
    xwv[i * 4 + 0] = f.x; xwv[i * 4 + 1] = f.y;
    xwv[i * 4 + 2] = f.z; xwv[i * 4 + 3] = f.w;
  }

  __syncthreads();

  step_body<0, true>(0, half, w, tid, lo, hi, bw, rdp, wrp, xwv, gp,
                     hx_peer, hx_self, h0row, peer_seq, self_seq);
  step_body<1, false>(1, half, w, tid, lo, hi, bw, rdp, wrp, xwv, gp,
                      hx_peer, hx_self, h0row, peer_seq, self_seq);
#pragma unroll 1
  for (int t = 2; t < T_S; t += 2) {
    step_body<0, false>(t, half, w, tid, lo, hi, bw, rdp, wrp, xwv, gp,
                        hx_peer, hx_self, h0row, peer_seq, self_seq);
    step_body<1, false>(t + 1, half, w, tid, lo, hi, bw, rdp, wrp, xwv, gp,
                        hx_peer, hx_self, h0row, peer_seq, self_seq);
  }
}

// ---------------------------------------------------------------------------
extern "C" void kernel_launch(void* const* d_in, const int* in_sizes, int n_in,
                              void* d_out, int out_size, void* d_ws, size_t ws_size,
                              hipStream_t stream) {
  const float* x  = (const float*)d_in[0];
  const float* h0 = (const float*)d_in[1];
  const float* Wx = (const float*)d_in[2];
  const float* Wh = (const float*)d_in[3];
  const float* b  = (const float*)d_in[4];
  float* out = (float*)d_out;

  char* ws = (char*)d_ws;
  uint4* whb = (uint4*)ws;                       // 512 KB
  uint4* wxb = (uint4*)(ws + 524288);            // 512 KB
  char* hx = ws + 2 * 524288;                    // 128 KB (4 grp x 2 half x 16 KB)
  unsigned* seq = (unsigned*)(ws + 2 * 524288 + 131072);  // 512 B flags

  (void)hipMemsetAsync(seq, 0, 512, stream);     // monotone flags start at 0

  prepack<<<1024, 64, 0, stream>>>(Wx, Wh, wxb, whb);
  gemm_xw<<<2048, 256, 0, stream>>>(x, wxb, b, out);
  rnn_scan<<<8, 512, 0, stream>>>(h0, whb, out, hx, seq);
}

// Round 11
// 2297.345 us; speedup vs baseline: 1.2124x; 1.2124x over previous
//
#include <hip/hip_runtime.h>

// N=64, T=512, D=H=512.
//   xw = x @ Wx + b   -> d_out (fp32), big MFMA GEMM
//   h_t = tanh(h_{t-1} @ Wh + xw_t) -> overwrites d_out in place
//
// rnn_scan v10 (round-10 lessons):
//  - Cross-CU exchange per step is unaffordable (r2 fence: 16us/step, v9
//    relaxed-agent: 5us/step) -> stay at 4 blocks, in-block exchange only.
//  - Physical reg pool = 2048/CU -> at 8 waves/CU each wave has <=256 unified
//    regs. v7's 192-frag AGPR array + 128 VGPR = 320 could NOT fit: compiler
//    silently reloaded ~4 kk from L2 per step, blocking at first use.
//  - v10 makes the split explicit: kk0-7 AGPR (128 regs), kk8-11 in 128 KB
//    LDS, kk12-15 STREAMED from L2 each step with early prefetch (kk12/13 at
//    step top, kk14/15 before phase B; consumed last). L2 latency hides under
//    the AGPR/LDS MFMA phases; 2 waves/SIMD interleave covers the rest.
//  - Accumulation order kk 0..15 unchanged -> bit-identical to v7 output.
//  Everything else from v7: swapped-operand MFMA, acc init from xw, xw(t+1)
//  prefetch at top, imm-offset LDS addressing, vector epilogue, ONE raw
//  s_barrier + lgkmcnt(0) per step. LDS = 128K wlds + 2x16K h = 160 KB.

typedef __attribute__((ext_vector_type(8))) short short8;
typedef __attribute__((ext_vector_type(4))) float f32x4;

#define DIM 512
#define T_S 512

union Frag { uint4 v; short8 s; unsigned short u[8]; };

static __device__ __forceinline__ unsigned short f2bf(float f) {
  union { float f; unsigned u; } v;
  v.f = f;
  unsigned r = v.u + 0x7FFFu + ((v.u >> 16) & 1u);
  return (unsigned short)(r >> 16);
}

static __device__ __forceinline__ unsigned cvt_pk_bf16(float a, float b) {
  unsigned r;
  asm("v_cvt_pk_bf16_f32 %0, %1, %2" : "=v"(r) : "v"(a), "v"(b));
  return r;  // lo16 = bf16(a), hi16 = bf16(b), RNE
}

static __device__ __forceinline__ float fast_tanh(float s) {
  float e = __builtin_amdgcn_exp2f(2.885390082f * s);
  return 1.0f - 2.0f * __builtin_amdgcn_rcpf(e + 1.0f);
}

// ---------------------------------------------------------------------------
// Pack W (512x512 fp32) into bf16 MFMA fragments (A/B-symmetric layout).
// Frag (kk, cc): lane l holds W[k=32kk+8(l>>4)+j][col=16cc+(l&15)], j=0..7,
// at dst[(kk*32+cc)*64 + lane].
// ---------------------------------------------------------------------------
__global__ __launch_bounds__(64) void prepack(const float* __restrict__ Wx,
                                              const float* __restrict__ Wh,
                                              uint4* __restrict__ wxb,
                                              uint4* __restrict__ whb) {
  int bid = blockIdx.x;
  int mat = bid >> 9;
  int idx = bid & 511;
  int kk = idx >> 5, cc = idx & 31;
  int lane = threadIdx.x;
  int lo = lane & 15, hi = lane >> 4;
  const float* src = mat ? Wh : Wx;
  uint4* dst = mat ? whb : wxb;
  int col = cc * 16 + lo;
  int kbase = kk * 32 + hi * 8;
  Frag fr;
#pragma unroll
  for (int j = 0; j < 8; ++j)
    fr.u[j] = f2bf(src[(size_t)(kbase + j) * DIM + col]);
  dst[(kk * 32 + cc) * 64 + lane] = fr.v;
}

// ---------------------------------------------------------------------------
// xw = x @ Wx + b -> out (fp32). M=32768, K=N=512. Unchanged.
// ---------------------------------------------------------------------------
__global__ __launch_bounds__(256) void gemm_xw(const float* __restrict__ x,
                                               const uint4* __restrict__ wxb,
                                               const float* __restrict__ bias,
                                               float* __restrict__ out) {
  int bid = blockIdx.x;
  int m = bid >> 2, nb = bid & 3;
  int wave = threadIdx.x >> 6, lane = threadIdx.x & 63;
  int lo = lane & 15, hi = lane >> 4;
  int rowbase = m * 64;
  int colbase = nb * 128 + wave * 32;

  f32x4 acc[4][2];
#pragma unroll
  for (int mi = 0; mi < 4; ++mi)
#pragma unroll
    for (int ni = 0; ni < 2; ++ni) acc[mi][ni] = (f32x4){0.f, 0.f, 0.f, 0.f};

  for (int kk = 0; kk < 16; ++kk) {
    short8 afrag[4];
#pragma unroll
    for (int mi = 0; mi < 4; ++mi) {
      const float* ap = x + (size_t)(rowbase + mi * 16 + lo) * DIM + kk * 32 + hi * 8;
      float4 f0 = *(const float4*)ap;
      float4 f1 = *(const float4*)(ap + 4);
      Frag a;
      a.u[0] = f2bf(f0.x); a.u[1] = f2bf(f0.y); a.u[2] = f2bf(f0.z); a.u[3] = f2bf(f0.w);
      a.u[4] = f2bf(f1.x); a.u[5] = f2bf(f1.y); a.u[6] = f2bf(f1.z); a.u[7] = f2bf(f1.w);
      afrag[mi] = a.s;
    }
#pragma unroll
    for (int ni = 0; ni < 2; ++ni) {
      int cc = nb * 8 + wave * 2 + ni;
      Frag b;
      b.v = wxb[(kk * 32 + cc) * 64 + lane];
#pragma unroll
      for (int mi = 0; mi < 4; ++mi)
        acc[mi][ni] = __builtin_amdgcn_mfma_f32_16x16x32_bf16(afrag[mi], b.s, acc[mi][ni], 0, 0, 0);
    }
  }
#pragma unroll
  for (int ni = 0; ni < 2; ++ni) {
    int col = colbase + ni * 16 + lo;
    float bv = bias[col];
#pragma unroll
    for (int mi = 0; mi < 4; ++mi)
#pragma unroll
      for (int r = 0; r < 4; ++r) {
        int row = rowbase + mi * 16 + hi * 4 + r;
        out[(size_t)row * DIM + col] = acc[mi][ni][r] + bv;
      }
  }
}

// ---------------------------------------------------------------------------
// Recurrent scan v10. grid = 4 blocks x 512 thr (8 waves, 2/SIMD).
// Block g: batch rows [16g,16g+16), all 512 cols. Wave w: cols [64w,64w+64).
// h in LDS as [buf][n][k] bf16, XOR-swizzled: byte = n*1024 + ((k*2)^((n&7)<<4)).
// Weights: kk0-7 AGPR (bw, 128 regs), kk8-11 LDS (wlds), kk12-15 L2-streamed.
// ---------------------------------------------------------------------------
__shared__ uint4 wlds[4][32][64];             // 128 KB: Wh kk=8..11
__shared__ unsigned short hbuf2[2][16 * 512]; // 32 KB ping/pong

template <int BUF>
static __device__ __forceinline__ void step_body(
    int t, int w, int lane, const uint4 (&bw)[8][4],
    const uint4* const (&wp)[4],            // kk12..15 frag rows in whb (L2)
    const uint4* const (&rdp)[8], uint2* const (&wrp)[4],
    float (&xwv)[16], float*& gp) {
  // acc starts at xw (lane: n=lo, cols 64w + 16i + 4hi + r)
  f32x4 acc[4];
#pragma unroll
  for (int i = 0; i < 4; ++i)
    acc[i] = (f32x4){xwv[i * 4 + 0], xwv[i * 4 + 1], xwv[i * 4 + 2], xwv[i * 4 + 3]};

  // prefetch xw(t+1): 4x dwordx4
  const float* lp = gp + ((t < T_S - 1) ? DIM : 0);
#pragma unroll
  for (int i = 0; i < 4; ++i) {
    float4 f = *(const float4*)(lp + i * 16);
    xwv[i * 4 + 0] = f.x; xwv[i * 4 + 1] = f.y;
    xwv[i * 4 + 2] = f.z; xwv[i * 4 + 3] = f.w;
  }

  // stream-prefetch Wh kk12,13 from L2 (consumed in phase C, ~2000 cy later)
  uint4 swA[2][4];
#pragma unroll
  for (int k2 = 0; k2 < 2; ++k2)
#pragma unroll
    for (int i = 0; i < 4; ++i) swA[k2][i] = wp[k2][i * 64];  // +1024B imm

  // phase A: kk0..7, weights from AGPR
#pragma unroll
  for (int kk = 0; kk < 8; ++kk) {
    Frag hf; hf.v = rdp[kk][BUF * 1024];
#pragma unroll
    for (int i = 0; i < 4; ++i) {
      Frag a; a.v = bw[kk][i];
      acc[i] = __builtin_amdgcn_mfma_f32_16x16x32_bf16(a.s, hf.s, acc[i], 0, 0, 0);
    }
  }

  // stream-prefetch Wh kk14,15
  uint4 swB[2][4];
#pragma unroll
  for (int k2 = 0; k2 < 2; ++k2)
#pragma unroll
    for (int i = 0; i < 4; ++i) swB[k2][i] = wp[2 + k2][i * 64];

  // phase B: kk8..11, weights from LDS
#pragma unroll
  for (int kk = 8; kk < 12; ++kk) {
    Frag hf; hf.v = rdp[kk & 7][32 + BUF * 1024];
#pragma unroll
    for (int i = 0; i < 4; ++i) {
      Frag a; a.v = wlds[kk - 8][w * 4 + i][lane];
      acc[i] = __builtin_amdgcn_mfma_f32_16x16x32_bf16(a.s, hf.s, acc[i], 0, 0, 0);
    }
  }

  // phase C: kk12..15, weights from the stream buffers
#pragma unroll
  for (int kk = 12; kk < 16; ++kk) {
    Frag hf; hf.v = rdp[kk & 7][32 + BUF * 1024];
#pragma unroll
    for (int i = 0; i < 4; ++i) {
      Frag a; a.v = (kk < 14) ? swA[kk - 12][i] : swB[kk - 14][i];
      acc[i] = __builtin_amdgcn_mfma_f32_16x16x32_bf16(a.s, hf.s, acc[i], 0, 0, 0);
    }
  }

  // epilogue: lane owns n=lo, 4 consecutive cols per acc group
#pragma unroll
  for (int i = 0; i < 4; ++i) {
    float h0 = fast_tanh(acc[i][0]);
    float h1 = fast_tanh(acc[i][1]);
    float h2 = fast_tanh(acc[i][2]);
    float h3 = fast_tanh(acc[i][3]);
    *(float4*)(gp + i * 16) = (float4){h0, h1, h2, h3};   // out row n, 16B
    uint2 u;
    u.x = cvt_pk_bf16(h0, h1);
    u.y = cvt_pk_bf16(h2, h3);
    wrp[i][(BUF ^ 1) * 2048] = u;                          // ds_write_b64
  }
  gp += DIM;

  // one barrier per step: LDS h-writes visible; no vmem drain
  asm volatile("s_waitcnt lgkmcnt(0)" ::: "memory");
  __builtin_amdgcn_sched_barrier(0);
  __builtin_amdgcn_s_barrier();
  __builtin_amdgcn_sched_barrier(0);
}

__global__ __launch_bounds__(512, 2) void rnn_scan(const float* __restrict__ h0,
                                                   const uint4* __restrict__ whb,
                                                   float* __restrict__ out) {
  int g = blockIdx.x;
  int w = threadIdx.x >> 6, lane = threadIdx.x & 63;
  int lo = lane & 15, hi = lane >> 4;
  int msk = (lo & 7) << 4;

  // AGPR-resident Wh: kk 0..7 x this wave's 4 col-tiles = 128 regs
  uint4 bw[8][4];
#pragma unroll
  for (int kk = 0; kk < 8; ++kk)
#pragma unroll
    for (int i = 0; i < 4; ++i)
      bw[kk][i] = whb[(kk * 32 + (w * 4 + i)) * 64 + lane];

  // LDS-resident Wh: kk 8..11, all 32 cc (coalesced cooperative stage)
#pragma unroll
  for (int e = 0; e < 16; ++e) {
    int idx = e * 512 + threadIdx.x;
    int s = idx >> 11, rem = idx & 2047;
    wlds[s][rem >> 6][rem & 63] = whb[((8 + s) * 32 + (rem >> 6)) * 64 + (rem & 63)];
  }

  // L2-stream bases for kk12..15 (loop-invariant; i via +1024B imm offset)
  const uint4* wp[4];
#pragma unroll
  for (int k = 0; k < 4; ++k)
    wp[k] = whb + ((12 + k) * 32 + w * 4) * 64 + lane;

  // loop-invariant LDS addresses (buffer 0 bases; +16384B via imm for buffer 1)
  // read (B=h frag): byte = lo*1024 + ((kk*64 + hi*16) ^ msk), kk=0..7
  const uint4* rdp[8];
#pragma unroll
  for (int kk = 0; kk < 8; ++kk)
    rdp[kk] = (const uint4*)((const char*)hbuf2 + lo * 1024 + ((kk * 64 + hi * 16) ^ msk));
  // write: byte = lo*1024 + (((64w + 16i + 4hi)*2) ^ msk), i=0..3 bases
  uint2* wrp[4];
#pragma unroll
  for (int i = 0; i < 4; ++i)
    wrp[i] = (uint2*)((char*)hbuf2 + lo * 1024 + ((128 * w + 32 * i + 8 * hi) ^ msk));

  // h_0 into buffer 0: lane loads h0[n=lo][c..c+3], packs, b64-writes
#pragma unroll
  for (int i = 0; i < 4; ++i) {
    const float* hp = h0 + (size_t)(g * 16 + lo) * DIM + w * 64 + i * 16 + hi * 4;
    float4 f = *(const float4*)hp;
    uint2 u;
    u.x = (unsigned)f2bf(f.x) | ((unsigned)f2bf(f.y) << 16);
    u.y = (unsigned)f2bf(f.z) | ((unsigned)f2bf(f.w) << 16);
    wrp[i][0] = u;
  }

  // running global pointer: lane -> out[n=16g+lo][t=0][64w + 4hi]
  float* gp = out + ((size_t)(g * 16 + lo) * T_S) * DIM + w * 64 + hi * 4;

  // prime xw for t=0
  float xwv[16];
#pragma unroll
  for (int i = 0; i < 4; ++i) {
    float4 f = *(const float4*)(gp + i * 16);
    xwv[i * 4 + 0] = f.x; xwv[i * 4 + 1] = f.y;
    xwv[i * 4 + 2] = f.z; xwv[i * 4 + 3] = f.w;
  }

  __syncthreads();  // heavy barrier once before the loop

#pragma unroll 1
  for (int t = 0; t < T_S; t += 2) {
    step_body<0>(t,     w, lane, bw, wp, rdp, wrp, xwv, gp);
    step_body<1>(t + 1, w, lane, bw, wp, rdp, wrp, xwv, gp);
  }
}

// ---------------------------------------------------------------------------
extern "C" void kernel_launch(void* const* d_in, const int* in_sizes, int n_in,
                              void* d_out, int out_size, void* d_ws, size_t ws_size,
                              hipStream_t stream) {
  const float* x  = (const float*)d_in[0];
  const float* h0 = (const float*)d_in[1];
  const float* Wx = (const float*)d_in[2];
  const float* Wh = (const float*)d_in[3];
  const float* b  = (const float*)d_in[4];
  float* out = (float*)d_out;

  char* ws = (char*)d_ws;
  uint4* whb = (uint4*)ws;                  // 512 KB
  uint4* wxb = (uint4*)(ws + 524288);       // 512 KB

  prepack<<<1024, 64, 0, stream>>>(Wx, Wh, wxb, whb);
  gemm_xw<<<2048, 256, 0, stream>>>(x, wxb, b, out);
  rnn_scan<<<4, 512, 0, stream>>>(h0, whb, out);
}

// Round 12
// 1763.927 us; speedup vs baseline: 1.5790x; 1.3024x over previous
//
#include <hip/hip_runtime.h>

// N=64, T=512, D=H=512.
//   xw = x @ Wx + b   -> d_out (fp32), big MFMA GEMM
//   h_t = tanh(h_{t-1} @ Wh + xw_t) -> overwrites d_out in place
//
// rnn_scan v11 (round-11 lessons):
//  - v10's L2 weight streaming costs ~2300 cy/step (128KB/CU/step at ~56B/cy
//    L2->CU) — MORE than the LDS reads it replaced. L2 streaming is dead.
//  - Therefore v7 really did keep 192 frags in AGPR (no silent reload):
//    at 2 waves/SIMD, 384 AGPR/SIMD works (v7), 512 fails (v8).
//  - v7's binding floor is LDS (~3900 cy/CU/step) > MFMA (2483 cy/SIMD).
//    v11 moves 2 more kk from LDS to AGPR: bw[14][4] = 224 AGPR/wave
//    (448/SIMD, inside the proven-good range), wlds = kk14,15 only (64 KB).
//    Weight-LDS reads halve: 16 -> 8 per wave per step.
//  - Accumulation order kk 0..15 unchanged -> bit-identical output.
//  Everything else from v7: swapped-operand MFMA (lane owns n=lo, 4 cols per
//  acc group), acc init from xw, xw(t+1) prefetch at step top, imm-offset
//  LDS addressing, vector epilogue (cvt_pk_bf16 + b64 writes), ONE raw
//  s_barrier + lgkmcnt(0) per step. LDS = 64K wlds + 2x16K h = 96 KB.

typedef __attribute__((ext_vector_type(8))) short short8;
typedef __attribute__((ext_vector_type(4))) float f32x4;

#define DIM 512
#define T_S 512

union Frag { uint4 v; short8 s; unsigned short u[8]; };

static __device__ __forceinline__ unsigned short f2bf(float f) {
  union { float f; unsigned u; } v;
  v.f = f;
  unsigned r = v.u + 0x7FFFu + ((v.u >> 16) & 1u);
  return (unsigned short)(r >> 16);
}

static __device__ __forceinline__ unsigned cvt_pk_bf16(float a, float b) {
  unsigned r;
  asm("v_cvt_pk_bf16_f32 %0, %1, %2" : "=v"(r) : "v"(a), "v"(b));
  return r;  // lo16 = bf16(a), hi16 = bf16(b), RNE
}

static __device__ __forceinline__ float fast_tanh(float s) {
  float e = __builtin_amdgcn_exp2f(2.885390082f * s);
  return 1.0f - 2.0f * __builtin_amdgcn_rcpf(e + 1.0f);
}

// ---------------------------------------------------------------------------
// Pack W (512x512 fp32) into bf16 MFMA fragments (A/B-symmetric layout).
// Frag (kk, cc): lane l holds W[k=32kk+8(l>>4)+j][col=16cc+(l&15)], j=0..7,
// at dst[(kk*32+cc)*64 + lane].
// ---------------------------------------------------------------------------
__global__ __launch_bounds__(64) void prepack(const float* __restrict__ Wx,
                                              const float* __restrict__ Wh,
                                              uint4* __restrict__ wxb,
                                              uint4* __restrict__ whb) {
  int bid = blockIdx.x;
  int mat = bid >> 9;
  int idx = bid & 511;
  int kk = idx >> 5, cc = idx & 31;
  int lane = threadIdx.x;
  int lo = lane & 15, hi = lane >> 4;
  const float* src = mat ? Wh : Wx;
  uint4* dst = mat ? whb : wxb;
  int col = cc * 16 + lo;
  int kbase = kk * 32 + hi * 8;
  Frag fr;
#pragma unroll
  for (int j = 0; j < 8; ++j)
    fr.u[j] = f2bf(src[(size_t)(kbase + j) * DIM + col]);
  dst[(kk * 32 + cc) * 64 + lane] = fr.v;
}

// ---------------------------------------------------------------------------
// xw = x @ Wx + b -> out (fp32). M=32768, K=N=512. Unchanged.
// ---------------------------------------------------------------------------
__global__ __launch_bounds__(256) void gemm_xw(const float* __restrict__ x,
                                               const uint4* __restrict__ wxb,
                                               const float* __restrict__ bias,
                                               float* __restrict__ out) {
  int bid = blockIdx.x;
  int m = bid >> 2, nb = bid & 3;
  int wave = threadIdx.x >> 6, lane = threadIdx.x & 63;
  int lo = lane & 15, hi = lane >> 4;
  int rowbase = m * 64;
  int colbase = nb * 128 + wave * 32;

  f32x4 acc[4][2];
#pragma unroll
  for (int mi = 0; mi < 4; ++mi)
#pragma unroll
    for (int ni = 0; ni < 2; ++ni) acc[mi][ni] = (f32x4){0.f, 0.f, 0.f, 0.f};

  for (int kk = 0; kk < 16; ++kk) {
    short8 afrag[4];
#pragma unroll
    for (int mi = 0; mi < 4; ++mi) {
      const float* ap = x + (size_t)(rowbase + mi * 16 + lo) * DIM + kk * 32 + hi * 8;
      float4 f0 = *(const float4*)ap;
      float4 f1 = *(const float4*)(ap + 4);
      Frag a;
      a.u[0] = f2bf(f0.x); a.u[1] = f2bf(f0.y); a.u[2] = f2bf(f0.z); a.u[3] = f2bf(f0.w);
      a.u[4] = f2bf(f1.x); a.u[5] = f2bf(f1.y); a.u[6] = f2bf(f1.z); a.u[7] = f2bf(f1.w);
      afrag[mi] = a.s;
    }
#pragma unroll
    for (int ni = 0; ni < 2; ++ni) {
      int cc = nb * 8 + wave * 2 + ni;
      Frag b;
      b.v = wxb[(kk * 32 + cc) * 64 + lane];
#pragma unroll
      for (int mi = 0; mi < 4; ++mi)
        acc[mi][ni] = __builtin_amdgcn_mfma_f32_16x16x32_bf16(afrag[mi], b.s, acc[mi][ni], 0, 0, 0);
    }
  }
#pragma unroll
  for (int ni = 0; ni < 2; ++ni) {
    int col = colbase + ni * 16 + lo;
    float bv = bias[col];
#pragma unroll
    for (int mi = 0; mi < 4; ++mi)
#pragma unroll
      for (int r = 0; r < 4; ++r) {
        int row = rowbase + mi * 16 + hi * 4 + r;
        out[(size_t)row * DIM + col] = acc[mi][ni][r] + bv;
      }
  }
}

// ---------------------------------------------------------------------------
// Recurrent scan v11. grid = 4 blocks x 512 thr (8 waves, 2/SIMD).
// Block g: batch rows [16g,16g+16), all 512 cols. Wave w: cols [64w,64w+64).
// h in LDS as [buf][n][k] bf16, XOR-swizzled: byte = n*1024 + ((k*2)^((n&7)<<4)).
// Weights: kk0-13 AGPR (bw, 224 regs), kk14-15 LDS (wlds, 64 KB).
// ---------------------------------------------------------------------------
__shared__ uint4 wlds[2][32][64];             // 64 KB: Wh kk=14,15
__shared__ unsigned short hbuf2[2][16 * 512]; // 32 KB ping/pong

template <int BUF>
static __device__ __forceinline__ void step_body(
    int t, int w, int lane, const uint4 (&bw)[14][4],
    const uint4* const (&rdp)[8], uint2* const (&wrp)[4],
    float (&xwv)[16], float*& gp) {
  // acc starts at xw (lane: n=lo, cols 64w + 16i + 4hi + r)
  f32x4 acc[4];
#pragma unroll
  for (int i = 0; i < 4; ++i)
    acc[i] = (f32x4){xwv[i * 4 + 0], xwv[i * 4 + 1], xwv[i * 4 + 2], xwv[i * 4 + 3]};

  // prefetch xw(t+1): 4x dwordx4, issued before MFMA phase
  const float* lp = gp + ((t < T_S - 1) ? DIM : 0);
#pragma unroll
  for (int i = 0; i < 4; ++i) {
    float4 f = *(const float4*)(lp + i * 16);
    xwv[i * 4 + 0] = f.x; xwv[i * 4 + 1] = f.y;
    xwv[i * 4 + 2] = f.z; xwv[i * 4 + 3] = f.w;
  }

  // kk 0..13: AGPR-resident weights; h frag from LDS (imm-offset reads)
#pragma unroll
  for (int kk = 0; kk < 14; ++kk) {
    Frag hf; hf.v = rdp[kk & 7][((kk & 8) ? 32 : 0) + BUF * 1024];
#pragma unroll
    for (int i = 0; i < 4; ++i) {
      Frag a; a.v = bw[kk][i];
      acc[i] = __builtin_amdgcn_mfma_f32_16x16x32_bf16(a.s, hf.s, acc[i], 0, 0, 0);
    }
  }
  // kk 14..15: LDS-resident weights (lane-contiguous uint4, conflict-free)
#pragma unroll
  for (int kk = 14; kk < 16; ++kk) {
    Frag hf; hf.v = rdp[kk & 7][32 + BUF * 1024];
#pragma unroll
    for (int i = 0; i < 4; ++i) {
      Frag a; a.v = wlds[kk - 14][w * 4 + i][lane];
      acc[i] = __builtin_amdgcn_mfma_f32_16x16x32_bf16(a.s, hf.s, acc[i], 0, 0, 0);
    }
  }

  // epilogue: lane owns n=lo, 4 consecutive cols per acc group
#pragma unroll
  for (int i = 0; i < 4; ++i) {
    float h0 = fast_tanh(acc[i][0]);
    float h1 = fast_tanh(acc[i][1]);
    float h2 = fast_tanh(acc[i][2]);
    float h3 = fast_tanh(acc[i][3]);
    *(float4*)(gp + i * 16) = (float4){h0, h1, h2, h3};   // out row n, 16B
    uint2 u;
    u.x = cvt_pk_bf16(h0, h1);
    u.y = cvt_pk_bf16(h2, h3);
    wrp[i][(BUF ^ 1) * 2048] = u;                          // ds_write_b64
  }
  gp += DIM;

  // one barrier per step: LDS h-writes visible; no vmem drain
  asm volatile("s_waitcnt lgkmcnt(0)" ::: "memory");
  __builtin_amdgcn_sched_barrier(0);
  __builtin_amdgcn_s_barrier();
  __builtin_amdgcn_sched_barrier(0);
}

__global__ __launch_bounds__(512, 2) void rnn_scan(const float* __restrict__ h0,
                                                   const uint4* __restrict__ whb,
                                                   float* __restrict__ out) {
  int g = blockIdx.x;
  int w = threadIdx.x >> 6, lane = threadIdx.x & 63;
  int lo = lane & 15, hi = lane >> 4;
  int msk = (lo & 7) << 4;

  // AGPR-resident Wh: kk 0..13 x this wave's 4 col-tiles = 224 regs
  uint4 bw[14][4];
#pragma unroll
  for (int kk = 0; kk < 14; ++kk)
#pragma unroll
    for (int i = 0; i < 4; ++i)
      bw[kk][i] = whb[(kk * 32 + (w * 4 + i)) * 64 + lane];

  // LDS-resident Wh: kk 14..15, all 32 cc (coalesced cooperative stage)
#pragma unroll
  for (int e = 0; e < 8; ++e) {
    int idx = e * 512 + threadIdx.x;
    int s = idx >> 11, rem = idx & 2047;
    wlds[s][rem >> 6][rem & 63] = whb[((14 + s) * 32 + (rem >> 6)) * 64 + (rem & 63)];
  }

  // loop-invariant LDS addresses (buffer 0 bases; +16384B via imm for buffer 1)
  // read (B=h frag): byte = lo*1024 + ((kk*64 + hi*16) ^ msk), kk=0..7
  const uint4* rdp[8];
#pragma unroll
  for (int kk = 0; kk < 8; ++kk)
    rdp[kk] = (const uint4*)((const char*)hbuf2 + lo * 1024 + ((kk * 64 + hi * 16) ^ msk));
  // write: byte = lo*1024 + (((64w + 16i + 4hi)*2) ^ msk), i=0..3 bases
  uint2* wrp[4];
#pragma unroll
  for (int i = 0; i < 4; ++i)
    wrp[i] = (uint2*)((char*)hbuf2 + lo * 1024 + ((128 * w + 32 * i + 8 * hi) ^ msk));

  // h_0 into buffer 0: lane loads h0[n=lo][c..c+3], packs, b64-writes
#pragma unroll
  for (int i = 0; i < 4; ++i) {
    const float* hp = h0 + (size_t)(g * 16 + lo) * DIM + w * 64 + i * 16 + hi * 4;
    float4 f = *(const float4*)hp;
    uint2 u;
    u.x = (unsigned)f2bf(f.x) | ((unsigned)f2bf(f.y) << 16);
    u.y = (unsigned)f2bf(f.z) | ((unsigned)f2bf(f.w) << 16);
    wrp[i][0] = u;
  }

  // running global pointer: lane -> out[n=16g+lo][t=0][64w + 4hi]
  float* gp = out + ((size_t)(g * 16 + lo) * T_S) * DIM + w * 64 + hi * 4;

  // prime xw for t=0
  float xwv[16];
#pragma unroll
  for (int i = 0; i < 4; ++i) {
    float4 f = *(const float4*)(gp + i * 16);
    xwv[i * 4 + 0] = f.x; xwv[i * 4 + 1] = f.y;
    xwv[i * 4 + 2] = f.z; xwv[i * 4 + 3] = f.w;
  }

  __syncthreads();  // heavy barrier once before the loop

#pragma unroll 1
  for (int t = 0; t < T_S; t += 2) {
    step_body<0>(t,     w, lane, bw, rdp, wrp, xwv, gp);
    step_body<1>(t + 1, w, lane, bw, rdp, wrp, xwv, gp);
  }
}

// ---------------------------------------------------------------------------
extern "C" void kernel_launch(void* const* d_in, const int* in_sizes, int n_in,
                              void* d_out, int out_size, void* d_ws, size_t ws_size,
                              hipStream_t stream) {
  const float* x  = (const float*)d_in[0];
  const float* h0 = (const float*)d_in[1];
  const float* Wx = (const float*)d_in[2];
  const float* Wh = (const float*)d_in[3];
  const float* b  = (const float*)d_in[4];
  float* out = (float*)d_out;

  char* ws = (char*)d_ws;
  uint4* whb = (uint4*)ws;                  // 512 KB
  uint4* wxb = (uint4*)(ws + 524288);       // 512 KB

  prepack<<<1024, 64, 0, stream>>>(Wx, Wh, wxb, whb);
  gemm_xw<<<2048, 256, 0, stream>>>(x, wxb, b, out);
  rnn_scan<<<4, 512, 0, stream>>>(h0, whb, out);
}

// Round 13
// 1511.824 us; speedup vs baseline: 1.8424x; 1.1668x over previous
//
#include <hip/hip_runtime.h>

// N=64, T=512, D=H=512.
//   xw = x @ Wx + b   -> d_out (fp32), big MFMA GEMM
//   h_t = tanh(h_{t-1} @ Wh + xw_t) -> overwrites d_out in place
//
// rnn_scan v12 = v7 (round-8 best: 1074us scan) + T5 setprio.
//  Register-placement axis exhausted (r9-r12): 192 AGPR weights/wave is the
//  optimum; 224/256 regress with no spill (allocator loses VGPR headroom for
//  the load/store pipeline). v7 structure restored verbatim:
//   - 8 waves (2/SIMD), wave owns 64 cols; bw[12][4]=192 AGPR + kk12-15 in
//     128KB LDS; h ping-pong 2x16KB (XOR-swizzled); swapped-operand MFMA;
//     acc init from xw; xw(t+1) prefetch at step top; imm-offset LDS bases;
//     vector epilogue; ONE raw s_barrier + lgkmcnt(0)/step.
//  NEW: s_setprio(1) around each 4-MFMA cluster (T5: pays when 2 waves/SIMD
//  sit in different phases — here they drift freely).
// gemm_xw v2: block tile 64x512 (x rows read once, not 4x); same kk order ->
//  bit-identical xw -> absmax must stay exactly 0.01843262.

typedef __attribute__((ext_vector_type(8))) short short8;
typedef __attribute__((ext_vector_type(4))) float f32x4;

#define DIM 512
#define T_S 512

union Frag { uint4 v; short8 s; unsigned short u[8]; };

static __device__ __forceinline__ unsigned short f2bf(float f) {
  union { float f; unsigned u; } v;
  v.f = f;
  unsigned r = v.u + 0x7FFFu + ((v.u >> 16) & 1u);
  return (unsigned short)(r >> 16);
}

static __device__ __forceinline__ unsigned cvt_pk_bf16(float a, float b) {
  unsigned r;
  asm("v_cvt_pk_bf16_f32 %0, %1, %2" : "=v"(r) : "v"(a), "v"(b));
  return r;  // lo16 = bf16(a), hi16 = bf16(b), RNE
}

static __device__ __forceinline__ float fast_tanh(float s) {
  float e = __builtin_amdgcn_exp2f(2.885390082f * s);
  return 1.0f - 2.0f * __builtin_amdgcn_rcpf(e + 1.0f);
}

// ---------------------------------------------------------------------------
// Pack W (512x512 fp32) into bf16 MFMA fragments (A/B-symmetric layout).
// Frag (kk, cc): lane l holds W[k=32kk+8(l>>4)+j][col=16cc+(l&15)], j=0..7,
// at dst[(kk*32+cc)*64 + lane].
// ---------------------------------------------------------------------------
__global__ __launch_bounds__(64) void prepack(const float* __restrict__ Wx,
                                              const float* __restrict__ Wh,
                                              uint4* __restrict__ wxb,
                                              uint4* __restrict__ whb) {
  int bid = blockIdx.x;
  int mat = bid >> 9;
  int idx = bid & 511;
  int kk = idx >> 5, cc = idx & 31;
  int lane = threadIdx.x;
  int lo = lane & 15, hi = lane >> 4;
  const float* src = mat ? Wh : Wx;
  uint4* dst = mat ? whb : wxb;
  int col = cc * 16 + lo;
  int kbase = kk * 32 + hi * 8;
  Frag fr;
#pragma unroll
  for (int j = 0; j < 8; ++j)
    fr.u[j] = f2bf(src[(size_t)(kbase + j) * DIM + col]);
  dst[(kk * 32 + cc) * 64 + lane] = fr.v;
}

// ---------------------------------------------------------------------------
// xw = x @ Wx + b -> out (fp32). M=32768, K=N=512.
// v2: block 256 thr (4 waves), tile 64 rows x 512 cols (x rows read ONCE).
// Wave w: cc 8w..8w+7. grid = 512. Same kk order -> bit-identical output.
// ---------------------------------------------------------------------------
__global__ __launch_bounds__(256, 2) void gemm_xw(const float* __restrict__ x,
                                                  const uint4* __restrict__ wxb,
                                                  const float* __restrict__ bias,
                                                  float* __restrict__ out) {
  int m = blockIdx.x;
  int wave = threadIdx.x >> 6, lane = threadIdx.x & 63;
  int lo = lane & 15, hi = lane >> 4;
  int rowbase = m * 64;

  f32x4 acc[4][8];
#pragma unroll
  for (int mi = 0; mi < 4; ++mi)
#pragma unroll
    for (int ni = 0; ni < 8; ++ni) acc[mi][ni] = (f32x4){0.f, 0.f, 0.f, 0.f};

  for (int kk = 0; kk < 16; ++kk) {
    short8 afrag[4];
#pragma unroll
    for (int mi = 0; mi < 4; ++mi) {
      const float* ap = x + (size_t)(rowbase + mi * 16 + lo) * DIM + kk * 32 + hi * 8;
      float4 f0 = *(const float4*)ap;
      float4 f1 = *(const float4*)(ap + 4);
      Frag a;
      a.u[0] = f2bf(f0.x); a.u[1] = f2bf(f0.y); a.u[2] = f2bf(f0.z); a.u[3] = f2bf(f0.w);
      a.u[4] = f2bf(f1.x); a.u[5] = f2bf(f1.y); a.u[6] = f2bf(f1.z); a.u[7] = f2bf(f1.w);
      afrag[mi] = a.s;
    }
#pragma unroll
    for (int ni = 0; ni < 8; ++ni) {
      int cc = wave * 8 + ni;
      Frag b;
      b.v = wxb[(kk * 32 + cc) * 64 + lane];
#pragma unroll
      for (int mi = 0; mi < 4; ++mi)
        acc[mi][ni] = __builtin_amdgcn_mfma_f32_16x16x32_bf16(afrag[mi], b.s, acc[mi][ni], 0, 0, 0);
    }
  }
#pragma unroll
  for (int ni = 0; ni < 8; ++ni) {
    int col = wave * 128 + ni * 16 + lo;
    float bv = bias[col];
#pragma unroll
    for (int mi = 0; mi < 4; ++mi)
#pragma unroll
      for (int r = 0; r < 4; ++r) {
        int row = rowbase + mi * 16 + hi * 4 + r;
        out[(size_t)row * DIM + col] = acc[mi][ni][r] + bv;
      }
  }
}

// ---------------------------------------------------------------------------
// Recurrent scan v12. grid = 4 blocks x 512 thr (8 waves, 2/SIMD).
// Block g: batch rows [16g,16g+16), all 512 cols. Wave w: cols [64w,64w+64).
// h in LDS as [buf][n][k] bf16, XOR-swizzled: byte = n*1024 + ((k*2)^((n&7)<<4)).
// ---------------------------------------------------------------------------
__shared__ uint4 wlds[4][32][64];             // 128 KB: Wh kk=12..15
__shared__ unsigned short hbuf2[2][16 * 512]; // 32 KB ping/pong

template <int BUF>
static __device__ __forceinline__ void step_body(
    int t, int w, int lane, const uint4 (&bw)[12][4],
    const uint4* const (&rdp)[8], uint2* const (&wrp)[4],
    float (&xwv)[16], float*& gp) {
  // acc starts at xw (lane: n=lo, cols 64w + 16i + 4hi + r)
  f32x4 acc[4];
#pragma unroll
  for (int i = 0; i < 4; ++i)
    acc[i] = (f32x4){xwv[i * 4 + 0], xwv[i * 4 + 1], xwv[i * 4 + 2], xwv[i * 4 + 3]};

  // prefetch xw(t+1): 4x dwordx4, issued before MFMA phase
  const float* lp = gp + ((t < T_S - 1) ? DIM : 0);
#pragma unroll
  for (int i = 0; i < 4; ++i) {
    float4 f = *(const float4*)(lp + i * 16);
    xwv[i * 4 + 0] = f.x; xwv[i * 4 + 1] = f.y;
    xwv[i * 4 + 2] = f.z; xwv[i * 4 + 3] = f.w;
  }

  // kk 0..11: AGPR-resident weights; h frag from LDS (imm-offset reads).
  // T5: raise priority only for the MFMA cluster.
#pragma unroll
  for (int kk = 0; kk < 12; ++kk) {
    Frag hf; hf.v = rdp[kk & 7][((kk & 8) ? 32 : 0) + BUF * 1024];
    __builtin_amdgcn_s_setprio(1);
#pragma unroll
    for (int i = 0; i < 4; ++i) {
      Frag a; a.v = bw[kk][i];
      acc[i] = __builtin_amdgcn_mfma_f32_16x16x32_bf16(a.s, hf.s, acc[i], 0, 0, 0);
    }
    __builtin_amdgcn_s_setprio(0);
  }
  // kk 12..15: LDS-resident weights (lane-contiguous uint4, conflict-free)
#pragma unroll
  for (int kk = 12; kk < 16; ++kk) {
    Frag hf; hf.v = rdp[kk & 7][32 + BUF * 1024];
    Frag a0; a0.v = wlds[kk - 12][w * 4 + 0][lane];
    Frag a1; a1.v = wlds[kk - 12][w * 4 + 1][lane];
    Frag a2; a2.v = wlds[kk - 12][w * 4 + 2][lane];
    Frag a3; a3.v = wlds[kk - 12][w * 4 + 3][lane];
    __builtin_amdgcn_s_setprio(1);
    acc[0] = __builtin_amdgcn_mfma_f32_16x16x32_bf16(a0.s, hf.s, acc[0], 0, 0, 0);
    acc[1] = __builtin_amdgcn_mfma_f32_16x16x32_bf16(a1.s, hf.s, acc[1], 0, 0, 0);
    acc[2] = __builtin_amdgcn_mfma_f32_16x16x32_bf16(a2.s, hf.s, acc[2], 0, 0, 0);
    acc[3] = __builtin_amdgcn_mfma_f32_16x16x32_bf16(a3.s, hf.s, acc[3], 0, 0, 0);
    __builtin_amdgcn_s_setprio(0);
  }

  // epilogue: lane owns n=lo, 4 consecutive cols per acc group
#pragma unroll
  for (int i = 0; i < 4; ++i) {
    float h0 = fast_tanh(acc[i][0]);
    float h1 = fast_tanh(acc[i][1]);
    float h2 = fast_tanh(acc[i][2]);
    float h3 = fast_tanh(acc[i][3]);
    *(float4*)(gp + i * 16) = (float4){h0, h1, h2, h3};   // out row n, 16B
    uint2 u;
    u.x = cvt_pk_bf16(h0, h1);
    u.y = cvt_pk_bf16(h2, h3);
    wrp[i][(BUF ^ 1) * 2048] = u;                          // ds_write_b64
  }
  gp += DIM;

  // one barrier per step: LDS h-writes visible; no vmem drain
  asm volatile("s_waitcnt lgkmcnt(0)" ::: "memory");
  __builtin_amdgcn_sched_barrier(0);
  __builtin_amdgcn_s_barrier();
  __builtin_amdgcn_sched_barrier(0);
}

__global__ __launch_bounds__(512, 2) void rnn_scan(const float* __restrict__ h0,
                                                   const uint4* __restrict__ whb,
                                                   float* __restrict__ out) {
  int g = blockIdx.x;
  int w = threadIdx.x >> 6, lane = threadIdx.x & 63;
  int lo = lane & 15, hi = lane >> 4;
  int msk = (lo & 7) << 4;

  // AGPR-resident Wh: kk 0..11 x this wave's 4 col-tiles = 192 regs
  uint4 bw[12][4];
#pragma unroll
  for (int kk = 0; kk < 12; ++kk)
#pragma unroll
    for (int i = 0; i < 4; ++i)
      bw[kk][i] = whb[(kk * 32 + (w * 4 + i)) * 64 + lane];

  // LDS-resident Wh: kk 12..15, all 32 cc (coalesced cooperative stage)
#pragma unroll
  for (int e = 0; e < 16; ++e) {
    int idx = e * 512 + threadIdx.x;
    int s = idx >> 11, rem = idx & 2047;
    wlds[s][rem >> 6][rem & 63] = whb[((12 + s) * 32 + (rem >> 6)) * 64 + (rem & 63)];
  }

  // loop-invariant LDS addresses (buffer 0 bases; +16384B via imm for buffer 1)
  // read (B=h frag): byte = lo*1024 + ((kk*64 + hi*16) ^ msk), kk=0..7
  const uint4* rdp[8];
#pragma unroll
  for (int kk = 0; kk < 8; ++kk)
    rdp[kk] = (const uint4*)((const char*)hbuf2 + lo * 1024 + ((kk * 64 + hi * 16) ^ msk));
  // write: byte = lo*1024 + (((64w + 16i + 4hi)*2) ^ msk), i=0..3 bases
  uint2* wrp[4];
#pragma unroll
  for (int i = 0; i < 4; ++i)
    wrp[i] = (uint2*)((char*)hbuf2 + lo * 1024 + ((128 * w + 32 * i + 8 * hi) ^ msk));

  // h_0 into buffer 0: lane loads h0[n=lo][c..c+3], packs, b64-writes
#pragma unroll
  for (int i = 0; i < 4; ++i) {
    const float* hp = h0 + (size_t)(g * 16 + lo) * DIM + w * 64 + i * 16 + hi * 4;
    float4 f = *(const float4*)hp;
    uint2 u;
    u.x = (unsigned)f2bf(f.x) | ((unsigned)f2bf(f.y) << 16);
    u.y = (unsigned)f2bf(f.z) | ((unsigned)f2bf(f.w) << 16);
    wrp[i][0] = u;
  }

  // running global pointer: lane -> out[n=16g+lo][t=0][64w + 4hi]
  float* gp = out + ((size_t)(g * 16 + lo) * T_S) * DIM + w * 64 + hi * 4;

  // prime xw for t=0
  float xwv[16];
#pragma unroll
  for (int i = 0; i < 4; ++i) {
    float4 f = *(const float4*)(gp + i * 16);
    xwv[i * 4 + 0] = f.x; xwv[i * 4 + 1] = f.y;
    xwv[i * 4 + 2] = f.z; xwv[i * 4 + 3] = f.w;
  }

  __syncthreads();  // heavy barrier once before the loop

#pragma unroll 1
  for (int t = 0; t < T_S; t += 2) {
    step_body<0>(t,     w, lane, bw, rdp, wrp, xwv, gp);
    step_body<1>(t + 1, w, lane, bw, rdp, wrp, xwv, gp);
  }
}

// ---------------------------------------------------------------------------
extern "C" void kernel_launch(void* const* d_in, const int* in_sizes, int n_in,
                              void* d_out, int out_size, void* d_ws, size_t ws_size,
                              hipStream_t stream) {
  const float* x  = (const float*)d_in[0];
  const float* h0 = (const float*)d_in[1];
  const float* Wx = (const float*)d_in[2];
  const float* Wh = (const float*)d_in[3];
  const float* b  = (const float*)d_in[4];
  float* out = (float*)d_out;

  char* ws = (char*)d_ws;
  uint4* whb = (uint4*)ws;                  // 512 KB
  uint4* wxb = (uint4*)(ws + 524288);       // 512 KB

  prepack<<<1024, 64, 0, stream>>>(Wx, Wh, wxb, whb);
  gemm_xw<<<512, 256, 0, stream>>>(x, wxb, b, out);
  rnn_scan<<<4, 512, 0, stream>>>(h0, whb, out);
}

// Round 14
// 1125.437 us; speedup vs baseline: 2.4749x; 1.3433x over previous
//
#include <hip/hip_runtime.h>

// N=64, T=512, D=H=512.
//   xw = x @ Wx + b   -> d_out (fp32), big MFMA GEMM
//   h_t = tanh(h_{t-1} @ Wh + xw_t) -> overwrites d_out in place
//
// rnn_scan v13 = v7 VERBATIM (round-8 best: 1074us scan).
//  Round-13 lesson: per-cluster s_setprio acted as scheduling fences inside
//  the compiler-pipelined kk loop (ds_read->MFMA overlap destroyed; both
//  MfmaUtil and VALUBusy dropped). Reverted. Register axis already exhausted
//  (r9-r12: 192 AGPR weights is the optimum).
//  Structure: 4 blocks x 8 waves (2/SIMD); wave owns 64 cols; bw[12][4]=192
//  AGPR + kk12-15 in 128KB LDS; h ping-pong 2x16KB XOR-swizzled; swapped
//  operand MFMA (lane owns n=lo, 4 consecutive cols/acc group); acc init from
//  xw; xw(t+1) prefetch at step top; imm-offset LDS bases; vector epilogue
//  (cvt_pk_bf16 + ds_write_b64 + float4 global store); ONE raw s_barrier +
//  lgkmcnt(0) per step.
// gemm_xw v2 kept (round-13 win: 64x512 block tile, x rows read once).

typedef __attribute__((ext_vector_type(8))) short short8;
typedef __attribute__((ext_vector_type(4))) float f32x4;

#define DIM 512
#define T_S 512

union Frag { uint4 v; short8 s; unsigned short u[8]; };

static __device__ __forceinline__ unsigned short f2bf(float f) {
  union { float f; unsigned u; } v;
  v.f = f;
  unsigned r = v.u + 0x7FFFu + ((v.u >> 16) & 1u);
  return (unsigned short)(r >> 16);
}

static __device__ __forceinline__ unsigned cvt_pk_bf16(float a, float b) {
  unsigned r;
  asm("v_cvt_pk_bf16_f32 %0, %1, %2" : "=v"(r) : "v"(a), "v"(b));
  return r;  // lo16 = bf16(a), hi16 = bf16(b), RNE
}

static __device__ __forceinline__ float fast_tanh(float s) {
  float e = __builtin_amdgcn_exp2f(2.885390082f * s);
  return 1.0f - 2.0f * __builtin_amdgcn_rcpf(e + 1.0f);
}

// ---------------------------------------------------------------------------
// Pack W (512x512 fp32) into bf16 MFMA fragments (A/B-symmetric layout).
// Frag (kk, cc): lane l holds W[k=32kk+8(l>>4)+j][col=16cc+(l&15)], j=0..7,
// at dst[(kk*32+cc)*64 + lane].
// ---------------------------------------------------------------------------
__global__ __launch_bounds__(64) void prepack(const float* __restrict__ Wx,
                                              const float* __restrict__ Wh,
                                              uint4* __restrict__ wxb,
                                              uint4* __restrict__ whb) {
  int bid = blockIdx.x;
  int mat = bid >> 9;
  int idx = bid & 511;
  int kk = idx >> 5, cc = idx & 31;
  int lane = threadIdx.x;
  int lo = lane & 15, hi = lane >> 4;
  const float* src = mat ? Wh : Wx;
  uint4* dst = mat ? whb : wxb;
  int col = cc * 16 + lo;
  int kbase = kk * 32 + hi * 8;
  Frag fr;
#pragma unroll
  for (int j = 0; j < 8; ++j)
    fr.u[j] = f2bf(src[(size_t)(kbase + j) * DIM + col]);
  dst[(kk * 32 + cc) * 64 + lane] = fr.v;
}

// ---------------------------------------------------------------------------
// xw = x @ Wx + b -> out (fp32). M=32768, K=N=512.
// v2: block 256 thr (4 waves), tile 64 rows x 512 cols (x rows read ONCE).
// Wave w: cc 8w..8w+7. grid = 512. Same kk order -> bit-identical output.
// ---------------------------------------------------------------------------
__global__ __launch_bounds__(256, 2) void gemm_xw(const float* __restrict__ x,
                                                  const uint4* __restrict__ wxb,
                                                  const float* __restrict__ bias,
                                                  float* __restrict__ out) {
  int m = blockIdx.x;
  int wave = threadIdx.x >> 6, lane = threadIdx.x & 63;
  int lo = lane & 15, hi = lane >> 4;
  int rowbase = m * 64;

  f32x4 acc[4][8];
#pragma unroll
  for (int mi = 0; mi < 4; ++mi)
#pragma unroll
    for (int ni = 0; ni < 8; ++ni) acc[mi][ni] = (f32x4){0.f, 0.f, 0.f, 0.f};

  for (int kk = 0; kk < 16; ++kk) {
    short8 afrag[4];
#pragma unroll
    for (int mi = 0; mi < 4; ++mi) {
      const float* ap = x + (size_t)(rowbase + mi * 16 + lo) * DIM + kk * 32 + hi * 8;
      float4 f0 = *(const float4*)ap;
      float4 f1 = *(const float4*)(ap + 4);
      Frag a;
      a.u[0] = f2bf(f0.x); a.u[1] = f2bf(f0.y); a.u[2] = f2bf(f0.z); a.u[3] = f2bf(f0.w);
      a.u[4] = f2bf(f1.x); a.u[5] = f2bf(f1.y); a.u[6] = f2bf(f1.z); a.u[7] = f2bf(f1.w);
      afrag[mi] = a.s;
    }
#pragma unroll
    for (int ni = 0; ni < 8; ++ni) {
      int cc = wave * 8 + ni;
      Frag b;
      b.v = wxb[(kk * 32 + cc) * 64 + lane];
#pragma unroll
      for (int mi = 0; mi < 4; ++mi)
        acc[mi][ni] = __builtin_amdgcn_mfma_f32_16x16x32_bf16(afrag[mi], b.s, acc[mi][ni], 0, 0, 0);
    }
  }
#pragma unroll
  for (int ni = 0; ni < 8; ++ni) {
    int col = wave * 128 + ni * 16 + lo;
    float bv = bias[col];
#pragma unroll
    for (int mi = 0; mi < 4; ++mi)
#pragma unroll
      for (int r = 0; r < 4; ++r) {
        int row = rowbase + mi * 16 + hi * 4 + r;
        out[(size_t)row * DIM + col] = acc[mi][ni][r] + bv;
      }
  }
}

// ---------------------------------------------------------------------------
// Recurrent scan v13 (= v7). grid = 4 blocks x 512 thr (8 waves, 2/SIMD).
// Block g: batch rows [16g,16g+16), all 512 cols. Wave w: cols [64w,64w+64).
// h in LDS as [buf][n][k] bf16, XOR-swizzled: byte = n*1024 + ((k*2)^((n&7)<<4)).
// ---------------------------------------------------------------------------
__shared__ uint4 wlds[4][32][64];             // 128 KB: Wh kk=12..15
__shared__ unsigned short hbuf2[2][16 * 512]; // 32 KB ping/pong

template <int BUF>
static __device__ __forceinline__ void step_body(
    int t, int w, int lane, const uint4 (&bw)[12][4],
    const uint4* const (&rdp)[8], uint2* const (&wrp)[4],
    float (&xwv)[16], float*& gp) {
  // acc starts at xw (lane: n=lo, cols 64w + 16i + 4hi + r)
  f32x4 acc[4];
#pragma unroll
  for (int i = 0; i < 4; ++i)
    acc[i] = (f32x4){xwv[i * 4 + 0], xwv[i * 4 + 1], xwv[i * 4 + 2], xwv[i * 4 + 3]};

  // prefetch xw(t+1): 4x dwordx4, issued before MFMA phase
  const float* lp = gp + ((t < T_S - 1) ? DIM : 0);
#pragma unroll
  for (int i = 0; i < 4; ++i) {
    float4 f = *(const float4*)(lp + i * 16);
    xwv[i * 4 + 0] = f.x; xwv[i * 4 + 1] = f.y;
    xwv[i * 4 + 2] = f.z; xwv[i * 4 + 3] = f.w;
  }

  // kk 0..11: AGPR-resident weights as A; h frag as B (imm-offset reads)
#pragma unroll
  for (int kk = 0; kk < 12; ++kk) {
    Frag hf; hf.v = rdp[kk & 7][((kk & 8) ? 32 : 0) + BUF * 1024];
#pragma unroll
    for (int i = 0; i < 4; ++i) {
      Frag a; a.v = bw[kk][i];
      acc[i] = __builtin_amdgcn_mfma_f32_16x16x32_bf16(a.s, hf.s, acc[i], 0, 0, 0);
    }
  }
  // kk 12..15: LDS-resident weights (lane-contiguous uint4, conflict-free)
#pragma unroll
  for (int kk = 12; kk < 16; ++kk) {
    Frag hf; hf.v = rdp[kk & 7][32 + BUF * 1024];
#pragma unroll
    for (int i = 0; i < 4; ++i) {
      Frag a; a.v = wlds[kk - 12][w * 4 + i][lane];
      acc[i] = __builtin_amdgcn_mfma_f32_16x16x32_bf16(a.s, hf.s, acc[i], 0, 0, 0);
    }
  }

  // epilogue: lane owns n=lo, 4 consecutive cols per acc group
#pragma unroll
  for (int i = 0; i < 4; ++i) {
    float h0 = fast_tanh(acc[i][0]);
    float h1 = fast_tanh(acc[i][1]);
    float h2 = fast_tanh(acc[i][2]);
    float h3 = fast_tanh(acc[i][3]);
    *(float4*)(gp + i * 16) = (float4){h0, h1, h2, h3};   // out row n, 16B
    uint2 u;
    u.x = cvt_pk_bf16(h0, h1);
    u.y = cvt_pk_bf16(h2, h3);
    wrp[i][(BUF ^ 1) * 2048] = u;                          // ds_write_b64
  }
  gp += DIM;

  // one barrier per step: LDS h-writes visible; no vmem drain
  asm volatile("s_waitcnt lgkmcnt(0)" ::: "memory");
  __builtin_amdgcn_sched_barrier(0);
  __builtin_amdgcn_s_barrier();
  __builtin_amdgcn_sched_barrier(0);
}

__global__ __launch_bounds__(512, 2) void rnn_scan(const float* __restrict__ h0,
                                                   const uint4* __restrict__ whb,
                                                   float* __restrict__ out) {
  int g = blockIdx.x;
  int w = threadIdx.x >> 6, lane = threadIdx.x & 63;
  int lo = lane & 15, hi = lane >> 4;
  int msk = (lo & 7) << 4;

  // AGPR-resident Wh: kk 0..11 x this wave's 4 col-tiles = 192 regs
  uint4 bw[12][4];
#pragma unroll
  for (int kk = 0; kk < 12; ++kk)
#pragma unroll
    for (int i = 0; i < 4; ++i)
      bw[kk][i] = whb[(kk * 32 + (w * 4 + i)) * 64 + lane];

  // LDS-resident Wh: kk 12..15, all 32 cc (coalesced cooperative stage)
#pragma unroll
  for (int e = 0; e < 16; ++e) {
    int idx = e * 512 + threadIdx.x;
    int s = idx >> 11, rem = idx & 2047;
    wlds[s][rem >> 6][rem & 63] = whb[((12 + s) * 32 + (rem >> 6)) * 64 + (rem & 63)];
  }

  // loop-invariant LDS addresses (buffer 0 bases; +16384B via imm for buffer 1)
  // read (B=h frag): byte = lo*1024 + ((kk*64 + hi*16) ^ msk), kk=0..7
  const uint4* rdp[8];
#pragma unroll
  for (int kk = 0; kk < 8; ++kk)
    rdp[kk] = (const uint4*)((const char*)hbuf2 + lo * 1024 + ((kk * 64 + hi * 16) ^ msk));
  // write: byte = lo*1024 + (((64w + 16i + 4hi)*2) ^ msk), i=0..3 bases
  uint2* wrp[4];
#pragma unroll
  for (int i = 0; i < 4; ++i)
    wrp[i] = (uint2*)((char*)hbuf2 + lo * 1024 + ((128 * w + 32 * i + 8 * hi) ^ msk));

  // h_0 into buffer 0: lane loads h0[n=lo][c..c+3], packs, b64-writes
#pragma unroll
  for (int i = 0; i < 4; ++i) {
    const float* hp = h0 + (size_t)(g * 16 + lo) * DIM + w * 64 + i * 16 + hi * 4;
    float4 f = *(const float4*)hp;
    uint2 u;
    u.x = (unsigned)f2bf(f.x) | ((unsigned)f2bf(f.y) << 16);
    u.y = (unsigned)f2bf(f.z) | ((unsigned)f2bf(f.w) << 16);
    wrp[i][0] = u;
  }

  // running global pointer: lane -> out[n=16g+lo][t=0][64w + 4hi]
  float* gp = out + ((size_t)(g * 16 + lo) * T_S) * DIM + w * 64 + hi * 4;

  // prime xw for t=0
  float xwv[16];
#pragma unroll
  for (int i = 0; i < 4; ++i) {
    float4 f = *(const float4*)(gp + i * 16);
    xwv[i * 4 + 0] = f.x; xwv[i * 4 + 1] = f.y;
    xwv[i * 4 + 2] = f.z; xwv[i * 4 + 3] = f.w;
  }

  __syncthreads();  // heavy barrier once before the loop

#pragma unroll 1
  for (int t = 0; t < T_S; t += 2) {
    step_body<0>(t,     w, lane, bw, rdp, wrp, xwv, gp);
    step_body<1>(t + 1, w, lane, bw, rdp, wrp, xwv, gp);
  }
}

// ---------------------------------------------------------------------------
extern "C" void kernel_launch(void* const* d_in, const int* in_sizes, int n_in,
                              void* d_out, int out_size, void* d_ws, size_t ws_size,
                              hipStream_t stream) {
  const float* x  = (const float*)d_in[0];
  const float* h0 = (const float*)d_in[1];
  const float* Wx = (const float*)d_in[2];
  const float* Wh = (const float*)d_in[3];
  const float* b  = (const float*)d_in[4];
  float* out = (float*)d_out;

  char* ws = (char*)d_ws;
  uint4* whb = (uint4*)ws;                  // 512 KB
  uint4* wxb = (uint4*)(ws + 524288);       // 512 KB

  prepack<<<1024, 64, 0, stream>>>(Wx, Wh, wxb, whb);
  gemm_xw<<<512, 256, 0, stream>>>(x, wxb, b, out);
  rnn_scan<<<4, 512, 0, stream>>>(h0, whb, out);
}